// Round 12
// baseline (145.561 us; speedup 1.0000x reference)
//
#include <hip/hip_runtime.h>

typedef __attribute__((ext_vector_type(8))) short short8;   // 8 x bf16 bits
typedef __attribute__((ext_vector_type(4))) float f32x4;
typedef __attribute__((ext_vector_type(4))) unsigned uint4v;

#define SPB 4    // samples per group (1 per wave)
#define NG  8    // groups per block
// LDS element geometry (u16 units); row strides EVEN so pair-reads are b32-aligned
#define XP_S   400              // 20*20 padded input tile
#define A1_ROW 12               // 12 padded cols (even)
#define A1_CH  (12 * A1_ROW)    // 144
#define A1_S   (12 * A1_CH)     // 1728 per sample
#define A2_S   200              // per-(wave,sample) a2 stride (192 used; 400B, 16B-aligned)
#define A3_S   40               // per-(wave,sample) a3 stride (32 used; 80B, 16B-aligned)

// Within-wave ordering fence for mixed-type LDS producer->consumer (u16 stores
// then b128 reads). r9 failed without this; __syncthreads (r10/r11) was an
// overkill fix — a2/a3 are wave-private, so a per-wave fence suffices.
#define WAVE_FENCE() do { \
    asm volatile("s_waitcnt lgkmcnt(0)" ::: "memory"); \
    __builtin_amdgcn_sched_barrier(0); \
} while (0)
#define COMPILER_FENCE() asm volatile("" ::: "memory")

__device__ __forceinline__ float fast_tanh(float x) {
    float e = __builtin_amdgcn_exp2f(x * 2.8853900817779268f);
    return 1.0f - 2.0f * __builtin_amdgcn_rcpf(e + 1.0f);
}
__device__ __forceinline__ unsigned short f2bf(float f) {
    unsigned u = __builtin_bit_cast(unsigned, f);
    return (unsigned short)((u + 0x7FFF + ((u >> 16) & 1)) >> 16);
}
__device__ __forceinline__ float bf2f(unsigned short h) {
    return __builtin_bit_cast(float, (unsigned)h << 16);
}

// k-slot permutation sigma for 5x5 patches (shared by A-pack and B-gather):
// slot m=8*hi+j -> pair P=min(m>>1,14), ky=P/3, q=P%3, c=2q+(m&1).
// Real iff c<5; c==5 and m>=30 are zero-weight garbage slots.

// launch_bounds (256,3): 170-VGPR cap -> no spill (r8/r11-proven; (256,4) spilled r10).
__global__ __launch_bounds__(256, 3) void lenet_mfma(
    const float* __restrict__ x,
    const float* __restrict__ w1, const float* __restrict__ b1,
    const float* __restrict__ w2, const float* __restrict__ b2,
    const float* __restrict__ w3, const float* __restrict__ b3,
    const float* __restrict__ ow, const float* __restrict__ ob,
    float* __restrict__ out)
{
    __shared__ __attribute__((aligned(16))) unsigned short wf3[6144];       // w3 A-frags
    __shared__ __attribute__((aligned(16))) unsigned short xp[SPB * XP_S];
    __shared__ __attribute__((aligned(16))) unsigned short a1[SPB * A1_S];
    __shared__ __attribute__((aligned(16))) unsigned short a2[16 * A2_S];   // [wv*4+q][k]
    __shared__ __attribute__((aligned(16))) unsigned short a3[16 * A3_S];   // [wv*4+q][unit]
    __shared__ unsigned short b1s[768];                                     // bf16 biases
    __shared__ float b2s[192], b3s[32], obs[16];

    const int t = threadIdx.x;
    const int lane = t & 63, wv = t >> 6;
    const int hi = lane >> 4, col = lane & 15;

    // issue group-0 x load first (1 float4/thread; latency hides under setup)
    const float4* xg = (const float4*)(x + (size_t)blockIdx.x * NG * SPB * 256);
    float4 v0 = xg[t];

    // ---- per-lane pair offsets (u16 units) for the sigma gather ----
    int po1[4], po2[4];
    #pragma unroll
    for (int pp = 0; pp < 4; ++pp) {
        int P = 4 * hi + pp; if (P > 14) P = 14;
        int ky = P / 3, q = P - 3 * ky;
        po1[pp] = ky * 20 + 2 * q;
        po2[pp] = ky * A1_ROW + 2 * q;
    }

    // ---- aw1/aw2 in registers (52 VGPRs); sigma-packed ----
    short8 aw1;
    #pragma unroll
    for (int j = 0; j < 8; ++j) {
        int m = 8 * hi + j; float val = 0.f;
        if (m < 30 && col < 12) {
            int P = m >> 1, ky = P / 3, q = P - 3 * ky, c = 2 * q + (m & 1);
            if (c < 5) val = w1[col * 25 + ky * 5 + c];
        }
        aw1[j] = (short)f2bf(val);
    }
    short8 aw2[12];
    #pragma unroll
    for (int ic = 0; ic < 12; ++ic) {
        #pragma unroll
        for (int j = 0; j < 8; ++j) {
            int m = 8 * hi + j; float val = 0.f;
            if (m < 30 && col < 12) {
                int P = m >> 1, ky = P / 3, q = P - 3 * ky, c = 2 * q + (m & 1);
                if (c < 5) {
                    int oc = col, icw;
                    if (oc < 4)      icw = (ic < 8) ? ic : -1;
                    else if (oc < 8) icw = (ic >= 4) ? ic - 4 : -1;
                    else             icw = (ic < 4) ? ic : ((ic >= 8) ? ic - 4 : -1);
                    if (icw >= 0) val = w2[(oc * 8 + icw) * 25 + ky * 5 + c];
                }
            }
            aw2[ic][j] = (short)f2bf(val);
        }
    }
    short8 awo;   // out-layer A-frag (4 VGPRs), identity k-order
    #pragma unroll
    for (int j = 0; j < 8; ++j) {
        int k = 8 * hi + j;
        awo[j] = (short)f2bf((col < 10 && k < 30) ? ow[k * 10 + col] : 0.f);
    }

    // ---- wf3: w3 A-frags in LDS (once/block) ----
    for (int e = t; e < 768; e += 256) {
        int fi = e >> 6, le = e & 63;
        int rt = fi / 6, kt = fi - 6 * rt;
        int unit = rt * 16 + (le & 15);
        short8 v;
        #pragma unroll
        for (int j = 0; j < 8; ++j) {
            int k = kt * 32 + 8 * (le >> 4) + j;
            v[j] = (short)f2bf((unit < 30) ? w3[k * 30 + unit] : 0.f);
        }
        *((short8*)wf3 + e) = v;
    }

    // ---- fills: pad rings -1 (persist), a3 zero, biases ----
    {
        unsigned* xpw = (unsigned*)xp;
        for (int i = t; i < SPB * XP_S / 2; i += 256) xpw[i] = 0xBF80BF80u;
        unsigned* a1w = (unsigned*)a1;
        for (int i = t; i < SPB * A1_S / 2; i += 256) a1w[i] = 0xBF80BF80u;
        unsigned* a3w = (unsigned*)a3;
        for (int i = t; i < 16 * A3_S / 2; i += 256) a3w[i] = 0u;
        for (int i = t; i < 768; i += 256) b1s[i] = f2bf(b1[i]);
        if (t < 192) b2s[t] = b2[t];
        if (t < 32)  b3s[t] = (t < 30) ? b3[t] : 0.f;
        if (t < 16)  obs[t] = (t < 10) ? ob[t] : 0.f;
    }
    __syncthreads();   // the ONLY block barrier: wf3/biases/pads published

    const int q1 = 40 * (col >> 3) + 2 * (col & 7);   // H1 patch TL (u16)
    const int q2 = 24 * (col >> 2) + 2 * (col & 3);   // H2 patch TL (u16)
    const unsigned* xp32 = (const unsigned*)xp;
    const unsigned* a132 = (const unsigned*)a1;
    const int colc = col & 3;

    // ================= group loop (no block barriers; waves independent) =================
    #pragma unroll 1
    for (int g = 0; g < NG; ++g) {
        // ---- scatter own-sample x into padded LDS (same-wave prod/cons) ----
        {
            int r = lane >> 2, c4 = (lane & 3) * 4;
            int base = wv * XP_S + (2 + r) * 20 + (2 + c4);   // even
            unsigned* dst = (unsigned*)xp + (base >> 1);
            dst[0] = (unsigned)f2bf(v0.x) | ((unsigned)f2bf(v0.y) << 16);
            dst[1] = (unsigned)f2bf(v0.z) | ((unsigned)f2bf(v0.w) << 16);
        }
        if (g + 1 < NG) v0 = xg[(g + 1) * 256 + t];   // prefetch next group
        COMPILER_FENCE();

        // ---- H1: wave's sample; 4 independent pos-tile MFMAs ----
        {
            int sbase = wv * XP_S + q1;
            #pragma unroll
            for (int pt = 0; pt < 4; ++pt) {
                int base = (sbase + pt * 80) >> 1;
                uint4v bu;
                #pragma unroll
                for (int pp = 0; pp < 4; ++pp) bu[pp] = xp32[base + (po1[pp] >> 1)];
                short8 b = __builtin_bit_cast(short8, bu);
                f32x4 acc = __builtin_amdgcn_mfma_f32_16x16x32_bf16(
                    aw1, b, (f32x4){0.f, 0.f, 0.f, 0.f}, 0, 0, 0);
                int p = pt * 16 + col;
                int oy = p >> 3, ox = p & 7;
                int wbase = wv * A1_S + (2 + oy) * A1_ROW + (2 + ox);
                #pragma unroll
                for (int jj = 0; jj < 4; ++jj) {
                    int oc = hi * 4 + jj;
                    if (oc < 12)
                        a1[wbase + oc * A1_CH] =
                            f2bf(fast_tanh(acc[jj] + bf2f(b1s[oc * 64 + p])));
                }
            }
        }
        COMPILER_FENCE();

        // ---- H2: two independent 6-MFMA chains (halved dep latency) ----
        {
            int sbase = wv * A1_S + q2;
            f32x4 acc0 = {0.f, 0.f, 0.f, 0.f};
            f32x4 acc1 = {0.f, 0.f, 0.f, 0.f};
            #pragma unroll
            for (int ic = 0; ic < 6; ++ic) {
                int b0 = (sbase + ic * A1_CH) >> 1;
                int b1i = (sbase + (ic + 6) * A1_CH) >> 1;
                uint4v u0, u1;
                #pragma unroll
                for (int pp = 0; pp < 4; ++pp) {
                    u0[pp] = a132[b0 + (po2[pp] >> 1)];
                    u1[pp] = a132[b1i + (po2[pp] >> 1)];
                }
                short8 p0 = __builtin_bit_cast(short8, u0);
                short8 p1 = __builtin_bit_cast(short8, u1);
                acc0 = __builtin_amdgcn_mfma_f32_16x16x32_bf16(aw2[ic], p0, acc0, 0, 0, 0);
                acc1 = __builtin_amdgcn_mfma_f32_16x16x32_bf16(aw2[ic + 6], p1, acc1, 0, 0, 0);
            }
            int sg = wv * 4 + (g & 3);
            #pragma unroll
            for (int jj = 0; jj < 4; ++jj) {
                int oc = hi * 4 + jj;
                if (oc < 12)
                    a2[sg * A2_S + oc * 16 + col] =
                        f2bf(fast_tanh(acc0[jj] + acc1[jj] + b2s[oc * 16 + col]));
            }
        }

        // ---- every 4 groups: per-wave H3 (own 4 samples) + out ----
        if ((g & 3) == 3) {
            WAVE_FENCE();   // a2 u16 stores complete before b128 reads (wave-private)
            #pragma unroll
            for (int rt = 0; rt < 2; ++rt) {
                f32x4 acc = {0.f, 0.f, 0.f, 0.f};
                #pragma unroll
                for (int kt = 0; kt < 6; ++kt) {
                    short8 a = *((const short8*)wf3 + (rt * 6 + kt) * 64 + lane);
                    short8 b = *(const short8*)&a2[(wv * 4 + colc) * A2_S + kt * 32 + 8 * hi];
                    acc = __builtin_amdgcn_mfma_f32_16x16x32_bf16(a, b, acc, 0, 0, 0);
                }
                #pragma unroll
                for (int jj = 0; jj < 4; ++jj) {
                    int unit = rt * 16 + hi * 4 + jj;
                    if (unit < 30 && col < 4)
                        a3[(wv * 4 + col) * A3_S + unit] =
                            f2bf(fast_tanh(acc[jj] + b3s[unit]));
                }
            }
            WAVE_FENCE();   // a3 u16 stores complete before b128 reads (wave-private)
            {
                short8 b = *(const short8*)&a3[(wv * 4 + colc) * A3_S + 8 * hi];
                f32x4 acc = __builtin_amdgcn_mfma_f32_16x16x32_bf16(
                    awo, b, (f32x4){0.f, 0.f, 0.f, 0.f}, 0, 0, 0);
                size_t sw = (size_t)blockIdx.x * (NG * SPB) + (g - 3) * 4 + 4 * col + wv;
                #pragma unroll
                for (int jj = 0; jj < 4; ++jj) {
                    int row = hi * 4 + jj;
                    if (row < 10 && col < 4)
                        out[sw * 10 + row] = fast_tanh(acc[jj] + obs[row]);
                }
            }
            COMPILER_FENCE();   // out reads ordered before next window's a2 writes
        }
    }
}

extern "C" void kernel_launch(void* const* d_in, const int* in_sizes, int n_in,
                              void* d_out, int out_size, void* d_ws, size_t ws_size,
                              hipStream_t stream) {
    const float* x  = (const float*)d_in[0];
    const float* w1 = (const float*)d_in[1];
    const float* b1 = (const float*)d_in[2];
    const float* w2 = (const float*)d_in[3];
    const float* b2 = (const float*)d_in[4];
    const float* w3 = (const float*)d_in[5];
    const float* b3 = (const float*)d_in[6];
    const float* ow = (const float*)d_in[7];
    const float* ob = (const float*)d_in[8];
    float* out = (float*)d_out;

    const int B = in_sizes[0] / 256;   // 65536 samples
    lenet_mfma<<<dim3(B / (SPB * NG)), dim3(256), 0, stream>>>(
        x, w1, b1, w2, b2, w3, b3, ow, ob, out);
}

// Round 14
// 119.078 us; speedup vs baseline: 1.2224x; 1.2224x over previous
//
#include <hip/hip_runtime.h>

typedef __attribute__((ext_vector_type(8))) short short8;   // 8 x bf16 bits
typedef __attribute__((ext_vector_type(4))) float f32x4;

#define SPB 4    // samples per group (1 per wave)
#define NG  8    // groups per block
// LDS element geometry (u16 units); row strides EVEN so pair-reads are b32-aligned
#define XP_S   400              // 20*20 padded input tile
#define A1_ROW 14               // 12 padded cols + 2 (even stride)
#define A1_CH  (12 * A1_ROW)    // 168
#define A1_S   (12 * A1_CH)     // 2016 per sample
#define A2_S   200              // per-slot a2 stride (192 used; 400B, 16B-aligned)
#define A3_S   40               // per-slot a3 stride (32 used; 80B, 16B-aligned)

__device__ __forceinline__ float fast_tanh(float x) {
    float e = __builtin_amdgcn_exp2f(x * 2.8853900817779268f);
    return 1.0f - 2.0f * __builtin_amdgcn_rcpf(e + 1.0f);
}
__device__ __forceinline__ unsigned short f2bf(float f) {
    unsigned u = __builtin_bit_cast(unsigned, f);
    return (unsigned short)((u + 0x7FFF + ((u >> 16) & 1)) >> 16);
}

// k-slot permutation sigma for 5x5 patches (shared by A-pack and B-gather):
// slot m=8*hi+j -> pair P=min(m>>1,14), ky=P/3, q=P%3, c=2q+(m&1).
// Real iff c<5; c==5 and m>=30 are zero-weight garbage slots.

// a2/a3 slot convention (r8): slot s = (g&3)*4 + wv  <->  global sample
// base + gw*4 + s (gw = window start group). H3 B-col = slot, out writes
// sw = base + (g>>2)*16 + col. DO NOT mix with the per-wave convention
// (wv*4+q) — r13 failed exactly on that mismatch.

// launch_bounds (256,3): 170-VGPR cap -> no spill (r8-proven; (256,4) spilled r10).
__global__ __launch_bounds__(256, 3) void lenet_mfma(
    const float* __restrict__ x,
    const float* __restrict__ w1, const float* __restrict__ b1,
    const float* __restrict__ w2, const float* __restrict__ b2,
    const float* __restrict__ w3, const float* __restrict__ b3,
    const float* __restrict__ ow, const float* __restrict__ ob,
    float* __restrict__ out)
{
    __shared__ __attribute__((aligned(16))) unsigned short wf3[6144];       // w3 A-frags
    __shared__ __attribute__((aligned(16))) unsigned short xp[SPB * XP_S];
    __shared__ __attribute__((aligned(16))) unsigned short a1[SPB * A1_S];
    __shared__ __attribute__((aligned(16))) unsigned short a2[16 * A2_S];   // [slot][k]
    __shared__ __attribute__((aligned(16))) unsigned short a3[16 * A3_S];   // [slot][unit]
    __shared__ float b1s[768], b2s[192], b3s[32], obs[16];

    const int t = threadIdx.x;
    const int lane = t & 63, wv = t >> 6;
    const int hi = lane >> 4, col = lane & 15;

    // issue group-0 x load first (1 float4/thread; latency hides under setup)
    const float4* xg = (const float4*)(x + (size_t)blockIdx.x * NG * SPB * 256);
    float4 v0 = xg[t];

    // ---- per-lane pair offsets (u16 units) for the sigma gather ----
    int po1[4], po2[4];
    #pragma unroll
    for (int pp = 0; pp < 4; ++pp) {
        int P = 4 * hi + pp; if (P > 14) P = 14;
        int ky = P / 3, q = P - 3 * ky;
        po1[pp] = ky * 20 + 2 * q;
        po2[pp] = ky * A1_ROW + 2 * q;
    }

    // ---- aw1/aw2 in registers (52 VGPRs, proven r8); sigma-packed ----
    short8 aw1;
    #pragma unroll
    for (int j = 0; j < 8; ++j) {
        int m = 8 * hi + j; float val = 0.f;
        if (m < 30 && col < 12) {
            int P = m >> 1, ky = P / 3, q = P - 3 * ky, c = 2 * q + (m & 1);
            if (c < 5) val = w1[col * 25 + ky * 5 + c];
        }
        aw1[j] = (short)f2bf(val);
    }
    short8 aw2[12];
    #pragma unroll
    for (int ic = 0; ic < 12; ++ic) {
        #pragma unroll
        for (int j = 0; j < 8; ++j) {
            int m = 8 * hi + j; float val = 0.f;
            if (m < 30 && col < 12) {
                int P = m >> 1, ky = P / 3, q = P - 3 * ky, c = 2 * q + (m & 1);
                if (c < 5) {
                    int oc = col, icw;
                    if (oc < 4)      icw = (ic < 8) ? ic : -1;
                    else if (oc < 8) icw = (ic >= 4) ? ic - 4 : -1;
                    else             icw = (ic < 4) ? ic : ((ic >= 8) ? ic - 4 : -1);
                    if (icw >= 0) val = w2[(oc * 8 + icw) * 25 + ky * 5 + c];
                }
            }
            aw2[ic][j] = (short)f2bf(val);
        }
    }
    short8 awo;   // out-layer A-frag (4 VGPRs), identity k-order
    #pragma unroll
    for (int j = 0; j < 8; ++j) {
        int k = 8 * hi + j;
        awo[j] = (short)f2bf((col < 10 && k < 30) ? ow[k * 10 + col] : 0.f);
    }

    // ---- wf3: w3 A-frags in LDS (once/block) ----
    for (int e = t; e < 768; e += 256) {
        int fi = e >> 6, le = e & 63;
        int rt = fi / 6, kt = fi - 6 * rt;
        int unit = rt * 16 + (le & 15);
        short8 v;
        #pragma unroll
        for (int j = 0; j < 8; ++j) {
            int k = kt * 32 + 8 * (le >> 4) + j;
            v[j] = (short)f2bf((unit < 30) ? w3[k * 30 + unit] : 0.f);
        }
        *((short8*)wf3 + e) = v;
    }

    // ---- fills: pad rings -1 (persist), a3 zero, biases ----
    {
        unsigned* xpw = (unsigned*)xp;
        for (int i = t; i < SPB * XP_S / 2; i += 256) xpw[i] = 0xBF80BF80u;
        unsigned* a1w = (unsigned*)a1;
        for (int i = t; i < SPB * A1_S / 2; i += 256) a1w[i] = 0xBF80BF80u;
        unsigned* a3w = (unsigned*)a3;
        for (int i = t; i < 16 * A3_S / 2; i += 256) a3w[i] = 0u;
        for (int i = t; i < 768; i += 256) b1s[i] = b1[i];
        if (t < 192) b2s[t] = b2[t];
        if (t < 32)  b3s[t] = (t < 30) ? b3[t] : 0.f;
        if (t < 16)  obs[t] = (t < 10) ? ob[t] : 0.f;
    }
    __syncthreads();

    const int q1 = 40 * (col >> 3) + 2 * (col & 7);   // H1 patch TL (u16)
    const int q2 = 28 * (col >> 2) + 2 * (col & 3);   // H2 patch TL (u16)
    const unsigned* xp32 = (const unsigned*)xp;
    const unsigned* a132 = (const unsigned*)a1;

    // ================= group loop =================
    #pragma unroll 1
    for (int g = 0; g < NG; ++g) {
        // ---- scatter own-sample x into padded LDS (same-wave prod/cons) ----
        {
            int r = lane >> 2, c4 = (lane & 3) * 4;
            int base = wv * XP_S + (2 + r) * 20 + (2 + c4);   // even
            unsigned* dst = (unsigned*)xp + (base >> 1);
            dst[0] = (unsigned)f2bf(v0.x) | ((unsigned)f2bf(v0.y) << 16);
            dst[1] = (unsigned)f2bf(v0.z) | ((unsigned)f2bf(v0.w) << 16);
        }
        if (g + 1 < NG) v0 = xg[(g + 1) * 256 + t];   // prefetch next group

        // ---- H1: gather ALL 4 fragments (16 dwords in flight), then 4 MFMAs,
        //      then epilogues (deepened outstanding-read window vs r8) ----
        {
            int sbase = wv * XP_S + q1;
            unsigned bu[4][4];
            #pragma unroll
            for (int pt = 0; pt < 4; ++pt) {
                int base = (sbase + pt * 80) >> 1;
                #pragma unroll
                for (int pp = 0; pp < 4; ++pp) bu[pt][pp] = xp32[base + (po1[pp] >> 1)];
            }
            f32x4 acc[4];
            #pragma unroll
            for (int pt = 0; pt < 4; ++pt) {
                short8 b;
                #pragma unroll
                for (int pp = 0; pp < 4; ++pp) {
                    unsigned r = bu[pt][pp];
                    b[2 * pp]     = (short)(r & 0xffff);
                    b[2 * pp + 1] = (short)(r >> 16);
                }
                acc[pt] = __builtin_amdgcn_mfma_f32_16x16x32_bf16(
                    aw1, b, (f32x4){0.f, 0.f, 0.f, 0.f}, 0, 0, 0);
            }
            #pragma unroll
            for (int pt = 0; pt < 4; ++pt) {
                int p = pt * 16 + col;
                int oy = p >> 3, ox = p & 7;
                int wbase = wv * A1_S + (2 + oy) * A1_ROW + (2 + ox);
                #pragma unroll
                for (int jj = 0; jj < 4; ++jj) {
                    int oc = hi * 4 + jj;
                    if (oc < 12)
                        a1[wbase + oc * A1_CH] =
                            f2bf(fast_tanh(acc[pt][jj] + b1s[oc * 64 + p]));
                }
            }
        }

        // ---- H2: 4 ic per step (16 dwords in flight); two acc chains ----
        {
            int sbase = wv * A1_S + q2;
            f32x4 acc0 = {0.f, 0.f, 0.f, 0.f};
            f32x4 acc1 = {0.f, 0.f, 0.f, 0.f};
            #pragma unroll
            for (int icp = 0; icp < 3; ++icp) {
                const int icA = 2 * icp, icB = 2 * icp + 1;
                int bA0 = (sbase + icA * A1_CH) >> 1;
                int bB0 = (sbase + icB * A1_CH) >> 1;
                int bA1 = (sbase + (icA + 6) * A1_CH) >> 1;
                int bB1 = (sbase + (icB + 6) * A1_CH) >> 1;
                unsigned uA0[4], uB0[4], uA1[4], uB1[4];
                #pragma unroll
                for (int pp = 0; pp < 4; ++pp) {
                    int o = po2[pp] >> 1;
                    uA0[pp] = a132[bA0 + o];
                    uB0[pp] = a132[bB0 + o];
                    uA1[pp] = a132[bA1 + o];
                    uB1[pp] = a132[bB1 + o];
                }
                short8 pA0, pB0, pA1, pB1;
                #pragma unroll
                for (int pp = 0; pp < 4; ++pp) {
                    pA0[2 * pp] = (short)(uA0[pp] & 0xffff); pA0[2 * pp + 1] = (short)(uA0[pp] >> 16);
                    pB0[2 * pp] = (short)(uB0[pp] & 0xffff); pB0[2 * pp + 1] = (short)(uB0[pp] >> 16);
                    pA1[2 * pp] = (short)(uA1[pp] & 0xffff); pA1[2 * pp + 1] = (short)(uA1[pp] >> 16);
                    pB1[2 * pp] = (short)(uB1[pp] & 0xffff); pB1[2 * pp + 1] = (short)(uB1[pp] >> 16);
                }
                acc0 = __builtin_amdgcn_mfma_f32_16x16x32_bf16(aw2[icA], pA0, acc0, 0, 0, 0);
                acc0 = __builtin_amdgcn_mfma_f32_16x16x32_bf16(aw2[icB], pB0, acc0, 0, 0, 0);
                acc1 = __builtin_amdgcn_mfma_f32_16x16x32_bf16(aw2[icA + 6], pA1, acc1, 0, 0, 0);
                acc1 = __builtin_amdgcn_mfma_f32_16x16x32_bf16(aw2[icB + 6], pB1, acc1, 0, 0, 0);
            }
            int sg = (g & 3) * 4 + wv;   // r8 slot convention (r13 bug was wv*4+(g&3))
            #pragma unroll
            for (int jj = 0; jj < 4; ++jj) {
                int oc = hi * 4 + jj;
                if (oc < 12)
                    a2[sg * A2_S + oc * 16 + col] =
                        f2bf(fast_tanh(acc0[jj] + acc1[jj] + b2s[oc * 16 + col]));
            }
        }

        // ---- every 4 groups: H3 (waves 0,1; N=16 samples) + out (wave 0) ----
        if ((g & 3) == 3) {
            __syncthreads();   // a2 (16 slots) complete
            if (wv < 2) {
                int rt = wv;
                f32x4 acc = {0.f, 0.f, 0.f, 0.f};
                #pragma unroll
                for (int kt = 0; kt < 6; ++kt) {
                    short8 a = *((const short8*)wf3 + (rt * 6 + kt) * 64 + lane);
                    short8 b = *(const short8*)&a2[col * A2_S + kt * 32 + 8 * hi];
                    acc = __builtin_amdgcn_mfma_f32_16x16x32_bf16(a, b, acc, 0, 0, 0);
                }
                #pragma unroll
                for (int jj = 0; jj < 4; ++jj) {
                    int unit = rt * 16 + hi * 4 + jj;
                    if (unit < 30)
                        a3[col * A3_S + unit] = f2bf(fast_tanh(acc[jj] + b3s[unit]));
                }
            }
            __syncthreads();   // a3 cross-wave
            if (wv == 0) {
                short8 b = *(const short8*)&a3[col * A3_S + 8 * hi];
                f32x4 acc = __builtin_amdgcn_mfma_f32_16x16x32_bf16(
                    awo, b, (f32x4){0.f, 0.f, 0.f, 0.f}, 0, 0, 0);
                size_t sw = (size_t)blockIdx.x * (NG * SPB) + (g >> 2) * 16 + col;
                #pragma unroll
                for (int jj = 0; jj < 4; ++jj) {
                    int row = hi * 4 + jj;
                    if (row < 10)
                        out[sw * 10 + row] = fast_tanh(acc[jj] + obs[row]);
                }
            }
            __syncthreads();   // a2/a3 free for next window
        }
    }
}

extern "C" void kernel_launch(void* const* d_in, const int* in_sizes, int n_in,
                              void* d_out, int out_size, void* d_ws, size_t ws_size,
                              hipStream_t stream) {
    const float* x  = (const float*)d_in[0];
    const float* w1 = (const float*)d_in[1];
    const float* b1 = (const float*)d_in[2];
    const float* w2 = (const float*)d_in[3];
    const float* b2 = (const float*)d_in[4];
    const float* w3 = (const float*)d_in[5];
    const float* b3 = (const float*)d_in[6];
    const float* ow = (const float*)d_in[7];
    const float* ob = (const float*)d_in[8];
    float* out = (float*)d_out;

    const int B = in_sizes[0] / 256;   // 65536 samples
    lenet_mfma<<<dim3(B / (SPB * NG)), dim3(256), 0, stream>>>(
        x, w1, b1, w2, b2, w3, b3, ow, ob, out);
}

// Round 15
// 109.237 us; speedup vs baseline: 1.3325x; 1.0901x over previous
//
#include <hip/hip_runtime.h>

typedef __attribute__((ext_vector_type(8))) short short8;   // 8 x bf16 bits
typedef __attribute__((ext_vector_type(4))) float f32x4;

#define SPB 4    // samples per group (1 per wave)
#define NG  8    // groups per block
// LDS element geometry (u16 units); row strides EVEN so pair-reads are b32-aligned
#define XP_S   400              // 20*20 padded input tile
#define A1_ROW 12               // 12 padded cols (even; r11-proven indices)
#define A1_CH  (12 * A1_ROW)    // 144
#define A1_S   (12 * A1_CH)     // 1728 per sample
#define A2_S   200              // per-slot a2 stride (192 used; 400B, 16B-aligned)
#define A3_S   40               // per-slot a3 stride (32 used; 80B, 16B-aligned)

__device__ __forceinline__ float fast_tanh(float x) {
    float e = __builtin_amdgcn_exp2f(x * 2.8853900817779268f);
    return 1.0f - 2.0f * __builtin_amdgcn_rcpf(e + 1.0f);
}
__device__ __forceinline__ unsigned short f2bf(float f) {
    unsigned u = __builtin_bit_cast(unsigned, f);
    return (unsigned short)((u + 0x7FFF + ((u >> 16) & 1)) >> 16);
}
__device__ __forceinline__ float bf2f(unsigned short h) {
    return __builtin_bit_cast(float, (unsigned)h << 16);
}

// k-slot permutation sigma for 5x5 patches (shared by A-pack and B-gather):
// slot m=8*hi+j -> pair P=min(m>>1,14), ky=P/3, q=P%3, c=2q+(m&1).
// Real iff c<5; c==5 and m>=30 are zero-weight garbage slots.

// a2/a3 slot convention (r8): slot s = (g&3)*4 + wv; H3 B-col = slot;
// out writes sw = base + (g>>2)*16 + col. Do NOT mix with wv*4+q (r13 bug).

// launch_bounds (256,3): 170-VGPR cap -> no spill (r8-proven; (256,4) spilled r10).
// LDS ~39.5KB -> hardware can fit 4 blocks/CU (the round-15 experiment).
__global__ __launch_bounds__(256, 3) void lenet_mfma(
    const float* __restrict__ x,
    const float* __restrict__ w1, const float* __restrict__ b1,
    const float* __restrict__ w2, const float* __restrict__ b2,
    const float* __restrict__ w3, const float* __restrict__ b3,
    const float* __restrict__ ow, const float* __restrict__ ob,
    float* __restrict__ out)
{
    __shared__ __attribute__((aligned(16))) unsigned short wf3[6144];       // w3 A-frags
    __shared__ __attribute__((aligned(16))) unsigned short xp[SPB * XP_S];
    __shared__ __attribute__((aligned(16))) unsigned short a1[SPB * A1_S];
    __shared__ __attribute__((aligned(16))) unsigned short a2[16 * A2_S];   // [slot][k]
    __shared__ __attribute__((aligned(16))) unsigned short a3[16 * A3_S];   // [slot][unit]
    __shared__ unsigned short b1s[768];                                     // bf16 biases
    __shared__ float b2s[192], b3s[32], obs[16];

    const int t = threadIdx.x;
    const int lane = t & 63, wv = t >> 6;
    const int hi = lane >> 4, col = lane & 15;

    // issue group-0 x load first (1 float4/thread; latency hides under setup)
    const float4* xg = (const float4*)(x + (size_t)blockIdx.x * NG * SPB * 256);
    float4 v0 = xg[t];

    // ---- per-lane pair offsets (u16 units) for the sigma gather ----
    int po1[4], po2[4];
    #pragma unroll
    for (int pp = 0; pp < 4; ++pp) {
        int P = 4 * hi + pp; if (P > 14) P = 14;
        int ky = P / 3, q = P - 3 * ky;
        po1[pp] = ky * 20 + 2 * q;
        po2[pp] = ky * A1_ROW + 2 * q;
    }

    // ---- aw1/aw2 in registers (52 VGPRs, proven r8); sigma-packed ----
    short8 aw1;
    #pragma unroll
    for (int j = 0; j < 8; ++j) {
        int m = 8 * hi + j; float val = 0.f;
        if (m < 30 && col < 12) {
            int P = m >> 1, ky = P / 3, q = P - 3 * ky, c = 2 * q + (m & 1);
            if (c < 5) val = w1[col * 25 + ky * 5 + c];
        }
        aw1[j] = (short)f2bf(val);
    }
    short8 aw2[12];
    #pragma unroll
    for (int ic = 0; ic < 12; ++ic) {
        #pragma unroll
        for (int j = 0; j < 8; ++j) {
            int m = 8 * hi + j; float val = 0.f;
            if (m < 30 && col < 12) {
                int P = m >> 1, ky = P / 3, q = P - 3 * ky, c = 2 * q + (m & 1);
                if (c < 5) {
                    int oc = col, icw;
                    if (oc < 4)      icw = (ic < 8) ? ic : -1;
                    else if (oc < 8) icw = (ic >= 4) ? ic - 4 : -1;
                    else             icw = (ic < 4) ? ic : ((ic >= 8) ? ic - 4 : -1);
                    if (icw >= 0) val = w2[(oc * 8 + icw) * 25 + ky * 5 + c];
                }
            }
            aw2[ic][j] = (short)f2bf(val);
        }
    }
    short8 awo;   // out-layer A-frag (4 VGPRs), identity k-order
    #pragma unroll
    for (int j = 0; j < 8; ++j) {
        int k = 8 * hi + j;
        awo[j] = (short)f2bf((col < 10 && k < 30) ? ow[k * 10 + col] : 0.f);
    }

    // ---- wf3: w3 A-frags in LDS (once/block) ----
    for (int e = t; e < 768; e += 256) {
        int fi = e >> 6, le = e & 63;
        int rt = fi / 6, kt = fi - 6 * rt;
        int unit = rt * 16 + (le & 15);
        short8 v;
        #pragma unroll
        for (int j = 0; j < 8; ++j) {
            int k = kt * 32 + 8 * (le >> 4) + j;
            v[j] = (short)f2bf((unit < 30) ? w3[k * 30 + unit] : 0.f);
        }
        *((short8*)wf3 + e) = v;
    }

    // ---- fills: pad rings -1 (persist), a3 zero, biases ----
    {
        unsigned* xpw = (unsigned*)xp;
        for (int i = t; i < SPB * XP_S / 2; i += 256) xpw[i] = 0xBF80BF80u;
        unsigned* a1w = (unsigned*)a1;
        for (int i = t; i < SPB * A1_S / 2; i += 256) a1w[i] = 0xBF80BF80u;
        unsigned* a3w = (unsigned*)a3;
        for (int i = t; i < 16 * A3_S / 2; i += 256) a3w[i] = 0u;
        for (int i = t; i < 768; i += 256) b1s[i] = f2bf(b1[i]);
        if (t < 192) b2s[t] = b2[t];
        if (t < 32)  b3s[t] = (t < 30) ? b3[t] : 0.f;
        if (t < 16)  obs[t] = (t < 10) ? ob[t] : 0.f;
    }
    __syncthreads();

    const int q1 = 40 * (col >> 3) + 2 * (col & 7);   // H1 patch TL (u16)
    const int q2 = 24 * (col >> 2) + 2 * (col & 3);   // H2 patch TL (u16, A1_ROW=12)
    const unsigned* xp32 = (const unsigned*)xp;
    const unsigned* a132 = (const unsigned*)a1;

    // ================= group loop =================
    #pragma unroll 1
    for (int g = 0; g < NG; ++g) {
        // ---- scatter own-sample x into padded LDS (same-wave prod/cons) ----
        {
            int r = lane >> 2, c4 = (lane & 3) * 4;
            int base = wv * XP_S + (2 + r) * 20 + (2 + c4);   // even
            unsigned* dst = (unsigned*)xp + (base >> 1);
            dst[0] = (unsigned)f2bf(v0.x) | ((unsigned)f2bf(v0.y) << 16);
            dst[1] = (unsigned)f2bf(v0.z) | ((unsigned)f2bf(v0.w) << 16);
        }
        if (g + 1 < NG) v0 = xg[(g + 1) * 256 + t];   // prefetch next group

        // ---- H1: wave's sample; 4 independent pos-tile MFMAs (r8 form) ----
        {
            int sbase = wv * XP_S + q1;
            #pragma unroll
            for (int pt = 0; pt < 4; ++pt) {
                int base = (sbase + pt * 80) >> 1;
                short8 b;
                #pragma unroll
                for (int pp = 0; pp < 4; ++pp) {
                    unsigned r = xp32[base + (po1[pp] >> 1)];
                    b[2 * pp]     = (short)(r & 0xffff);
                    b[2 * pp + 1] = (short)(r >> 16);
                }
                f32x4 acc = __builtin_amdgcn_mfma_f32_16x16x32_bf16(
                    aw1, b, (f32x4){0.f, 0.f, 0.f, 0.f}, 0, 0, 0);
                int p = pt * 16 + col;
                int oy = p >> 3, ox = p & 7;
                int wbase = wv * A1_S + (2 + oy) * A1_ROW + (2 + ox);
                #pragma unroll
                for (int jj = 0; jj < 4; ++jj) {
                    int oc = hi * 4 + jj;
                    if (oc < 12)
                        a1[wbase + oc * A1_CH] =
                            f2bf(fast_tanh(acc[jj] + bf2f(b1s[oc * 64 + p])));
                }
            }
        }

        // ---- H2: two independent 6-MFMA chains (r8 form) ----
        {
            int sbase = wv * A1_S + q2;
            f32x4 acc0 = {0.f, 0.f, 0.f, 0.f};
            f32x4 acc1 = {0.f, 0.f, 0.f, 0.f};
            #pragma unroll
            for (int ic = 0; ic < 6; ++ic) {
                int b0 = (sbase + ic * A1_CH) >> 1;
                int b1i = (sbase + (ic + 6) * A1_CH) >> 1;
                short8 p0, p1;
                #pragma unroll
                for (int pp = 0; pp < 4; ++pp) {
                    unsigned r0 = a132[b0 + (po2[pp] >> 1)];
                    unsigned r1 = a132[b1i + (po2[pp] >> 1)];
                    p0[2 * pp]     = (short)(r0 & 0xffff);
                    p0[2 * pp + 1] = (short)(r0 >> 16);
                    p1[2 * pp]     = (short)(r1 & 0xffff);
                    p1[2 * pp + 1] = (short)(r1 >> 16);
                }
                acc0 = __builtin_amdgcn_mfma_f32_16x16x32_bf16(aw2[ic], p0, acc0, 0, 0, 0);
                acc1 = __builtin_amdgcn_mfma_f32_16x16x32_bf16(aw2[ic + 6], p1, acc1, 0, 0, 0);
            }
            int sg = (g & 3) * 4 + wv;   // r8 slot convention
            #pragma unroll
            for (int jj = 0; jj < 4; ++jj) {
                int oc = hi * 4 + jj;
                if (oc < 12)
                    a2[sg * A2_S + oc * 16 + col] =
                        f2bf(fast_tanh(acc0[jj] + acc1[jj] + b2s[oc * 16 + col]));
            }
        }

        // ---- every 4 groups: H3 (waves 0,1; N=16 slots) + out (wave 0) ----
        if ((g & 3) == 3) {
            __syncthreads();   // a2 (16 slots) complete
            if (wv < 2) {
                int rt = wv;
                f32x4 acc = {0.f, 0.f, 0.f, 0.f};
                #pragma unroll
                for (int kt = 0; kt < 6; ++kt) {
                    short8 a = *((const short8*)wf3 + (rt * 6 + kt) * 64 + lane);
                    short8 b = *(const short8*)&a2[col * A2_S + kt * 32 + 8 * hi];
                    acc = __builtin_amdgcn_mfma_f32_16x16x32_bf16(a, b, acc, 0, 0, 0);
                }
                #pragma unroll
                for (int jj = 0; jj < 4; ++jj) {
                    int unit = rt * 16 + hi * 4 + jj;
                    if (unit < 30)
                        a3[col * A3_S + unit] = f2bf(fast_tanh(acc[jj] + b3s[unit]));
                }
            }
            __syncthreads();   // a3 cross-wave
            if (wv == 0) {
                short8 b = *(const short8*)&a3[col * A3_S + 8 * hi];
                f32x4 acc = __builtin_amdgcn_mfma_f32_16x16x32_bf16(
                    awo, b, (f32x4){0.f, 0.f, 0.f, 0.f}, 0, 0, 0);
                size_t sw = (size_t)blockIdx.x * (NG * SPB) + (g >> 2) * 16 + col;
                #pragma unroll
                for (int jj = 0; jj < 4; ++jj) {
                    int row = hi * 4 + jj;
                    if (row < 10)
                        out[sw * 10 + row] = fast_tanh(acc[jj] + obs[row]);
                }
            }
            __syncthreads();   // a2/a3 free for next window
        }
    }
}

extern "C" void kernel_launch(void* const* d_in, const int* in_sizes, int n_in,
                              void* d_out, int out_size, void* d_ws, size_t ws_size,
                              hipStream_t stream) {
    const float* x  = (const float*)d_in[0];
    const float* w1 = (const float*)d_in[1];
    const float* b1 = (const float*)d_in[2];
    const float* w2 = (const float*)d_in[3];
    const float* b2 = (const float*)d_in[4];
    const float* w3 = (const float*)d_in[5];
    const float* b3 = (const float*)d_in[6];
    const float* ow = (const float*)d_in[7];
    const float* ob = (const float*)d_in[8];
    float* out = (float*)d_out;

    const int B = in_sizes[0] / 256;   // 65536 samples
    lenet_mfma<<<dim3(B / (SPB * NG)), dim3(256), 0, stream>>>(
        x, w1, b1, w2, b2, w3, b3, ow, ob, out);
}

// Round 16
// 94.086 us; speedup vs baseline: 1.5471x; 1.1610x over previous
//
#include <hip/hip_runtime.h>

typedef __attribute__((ext_vector_type(8))) short short8;   // 8 x bf16 bits
typedef __attribute__((ext_vector_type(4))) float f32x4;

#define SPB 4    // samples per group (1 per wave)
#define NG  8    // groups per block
// LDS element geometry (u16 units); row strides EVEN so pair-reads are b32-aligned
#define XP_S   400              // 20*20 padded input tile
#define A1_ROW 12               // 12 padded cols (even)
#define A1_CH  148              // 12*12 rows + 4 pad (oc-stride = 74 dwords -> 12 distinct banks)
#define A1_S   (12 * A1_CH)     // 1776 per sample
#define A2_S   200              // per-slot a2 stride (192 used; 400B, 16B-aligned)
#define A3_S   40               // per-slot a3 stride (32 used; 80B, 16B-aligned)

__device__ __forceinline__ float fast_tanh(float x) {
    float e = __builtin_amdgcn_exp2f(x * 2.8853900817779268f);
    return 1.0f - 2.0f * __builtin_amdgcn_rcpf(e + 1.0f);
}
__device__ __forceinline__ unsigned short f2bf(float f) {
    unsigned u = __builtin_bit_cast(unsigned, f);
    return (unsigned short)((u + 0x7FFF + ((u >> 16) & 1)) >> 16);
}
__device__ __forceinline__ float bf2f(unsigned short h) {
    return __builtin_bit_cast(float, (unsigned)h << 16);
}
__device__ __forceinline__ unsigned pack2bf(float lo, float hi) {
    return (unsigned)f2bf(lo) | ((unsigned)f2bf(hi) << 16);
}

// k-slot permutation sigma for 5x5 patches (shared by both MFMA operands):
// slot m=8*hi+j -> pair P=min(m>>1,14), ky=P/3, q=P%3, c=2q+(m&1).
// Real iff c<5; c==5 and m>=30 are zero-weight garbage slots.

// OPERAND-SWAPPED MFMAs (r16): mfma(patch, weights, acc) -> D row=position,
// col=oc. Lane (col=oc, hi) owns 4 ADJACENT pixels p = tile + 4*hi + jj of one
// channel -> paired b32 stores, no same-dword lane collisions. A/B fragments
// have mirrored layouts so gather code and weight packs are unchanged vs r15.

// a2/a3 slot convention (r8): slot s = (g&3)*4 + wv; H3 B-col = slot;
// out writes sw = base + (g>>2)*16 + col.

// launch_bounds (256,3): 170-VGPR cap -> no spill (r8/r15-proven).
__global__ __launch_bounds__(256, 3) void lenet_mfma(
    const float* __restrict__ x,
    const float* __restrict__ w1, const float* __restrict__ b1,
    const float* __restrict__ w2, const float* __restrict__ b2,
    const float* __restrict__ w3, const float* __restrict__ b3,
    const float* __restrict__ ow, const float* __restrict__ ob,
    float* __restrict__ out)
{
    __shared__ __attribute__((aligned(16))) unsigned short wf3[6144];       // w3 A-frags
    __shared__ __attribute__((aligned(16))) unsigned short xp[SPB * XP_S];
    __shared__ __attribute__((aligned(16))) unsigned short a1[SPB * A1_S];
    __shared__ __attribute__((aligned(16))) unsigned short a2[16 * A2_S];   // [slot][oc*16+p]
    __shared__ __attribute__((aligned(16))) unsigned short a3[16 * A3_S];   // [slot][unit]
    __shared__ unsigned short b1s[768];                                     // bf16 biases
    __shared__ float b2s[192], b3s[32], obs[16];

    const int t = threadIdx.x;
    const int lane = t & 63, wv = t >> 6;
    const int hi = lane >> 4, col = lane & 15;

    // issue group-0 x load first (1 float4/thread; latency hides under setup)
    const float4* xg = (const float4*)(x + (size_t)blockIdx.x * NG * SPB * 256);
    float4 v0 = xg[t];

    // ---- per-lane pair offsets (u16 units) for the sigma gather ----
    int po1[4], po2[4];
    #pragma unroll
    for (int pp = 0; pp < 4; ++pp) {
        int P = 4 * hi + pp; if (P > 14) P = 14;
        int ky = P / 3, q = P - 3 * ky;
        po1[pp] = ky * 20 + 2 * q;
        po2[pp] = ky * A1_ROW + 2 * q;
    }

    // ---- aw1/aw2 in registers (52 VGPRs); sigma-packed (unchanged content) ----
    short8 aw1;
    #pragma unroll
    for (int j = 0; j < 8; ++j) {
        int m = 8 * hi + j; float val = 0.f;
        if (m < 30 && col < 12) {
            int P = m >> 1, ky = P / 3, q = P - 3 * ky, c = 2 * q + (m & 1);
            if (c < 5) val = w1[col * 25 + ky * 5 + c];
        }
        aw1[j] = (short)f2bf(val);
    }
    short8 aw2[12];
    #pragma unroll
    for (int ic = 0; ic < 12; ++ic) {
        #pragma unroll
        for (int j = 0; j < 8; ++j) {
            int m = 8 * hi + j; float val = 0.f;
            if (m < 30 && col < 12) {
                int P = m >> 1, ky = P / 3, q = P - 3 * ky, c = 2 * q + (m & 1);
                if (c < 5) {
                    int oc = col, icw;
                    if (oc < 4)      icw = (ic < 8) ? ic : -1;
                    else if (oc < 8) icw = (ic >= 4) ? ic - 4 : -1;
                    else             icw = (ic < 4) ? ic : ((ic >= 8) ? ic - 4 : -1);
                    if (icw >= 0) val = w2[(oc * 8 + icw) * 25 + ky * 5 + c];
                }
            }
            aw2[ic][j] = (short)f2bf(val);
        }
    }
    short8 awo;   // out-layer A-frag (4 VGPRs), identity k-order
    #pragma unroll
    for (int j = 0; j < 8; ++j) {
        int k = 8 * hi + j;
        awo[j] = (short)f2bf((col < 10 && k < 30) ? ow[k * 10 + col] : 0.f);
    }

    // ---- wf3: w3 A-frags in LDS (once/block) ----
    for (int e = t; e < 768; e += 256) {
        int fi = e >> 6, le = e & 63;
        int rt = fi / 6, kt = fi - 6 * rt;
        int unit = rt * 16 + (le & 15);
        short8 v;
        #pragma unroll
        for (int j = 0; j < 8; ++j) {
            int k = kt * 32 + 8 * (le >> 4) + j;
            v[j] = (short)f2bf((unit < 30) ? w3[k * 30 + unit] : 0.f);
        }
        *((short8*)wf3 + e) = v;
    }

    // ---- fills: pad rings -1 (persist), a3 zero, biases ----
    {
        unsigned* xpw = (unsigned*)xp;
        for (int i = t; i < SPB * XP_S / 2; i += 256) xpw[i] = 0xBF80BF80u;
        unsigned* a1w = (unsigned*)a1;
        for (int i = t; i < SPB * A1_S / 2; i += 256) a1w[i] = 0xBF80BF80u;
        unsigned* a3w = (unsigned*)a3;
        for (int i = t; i < 16 * A3_S / 2; i += 256) a3w[i] = 0u;
        for (int i = t; i < 768; i += 256) b1s[i] = f2bf(b1[i]);
        if (t < 192) b2s[t] = b2[t];
        if (t < 32)  b3s[t] = (t < 30) ? b3[t] : 0.f;
        if (t < 16)  obs[t] = (t < 10) ? ob[t] : 0.f;
    }
    __syncthreads();

    const int q1 = 40 * (col >> 3) + 2 * (col & 7);   // H1 patch TL (u16), pos=col
    const int q2 = 24 * (col >> 2) + 2 * (col & 3);   // H2 patch TL (u16), pos=col
    const unsigned* xp32 = (const unsigned*)xp;
    const unsigned* a132 = (const unsigned*)a1;

    // ================= group loop =================
    #pragma unroll 1
    for (int g = 0; g < NG; ++g) {
        // ---- scatter own-sample x into padded LDS (same-wave prod/cons) ----
        {
            int r = lane >> 2, c4 = (lane & 3) * 4;
            int base = wv * XP_S + (2 + r) * 20 + (2 + c4);   // even
            unsigned* dst = (unsigned*)xp + (base >> 1);
            dst[0] = pack2bf(v0.x, v0.y);
            dst[1] = pack2bf(v0.z, v0.w);
        }
        if (g + 1 < NG) v0 = xg[(g + 1) * 256 + t];   // prefetch next group

        // ---- H1: A=patch, B=weights; lane owns 4 adjacent pixels of oc=col ----
        {
            int sbase = wv * XP_S + q1;
            #pragma unroll
            for (int pt = 0; pt < 4; ++pt) {
                int base = (sbase + pt * 80) >> 1;
                short8 a;
                #pragma unroll
                for (int pp = 0; pp < 4; ++pp) {
                    unsigned r = xp32[base + (po1[pp] >> 1)];
                    a[2 * pp]     = (short)(r & 0xffff);
                    a[2 * pp + 1] = (short)(r >> 16);
                }
                f32x4 acc = __builtin_amdgcn_mfma_f32_16x16x32_bf16(
                    a, aw1, (f32x4){0.f, 0.f, 0.f, 0.f}, 0, 0, 0);
                if (col < 12) {
                    int p0 = pt * 16 + 4 * hi;          // 4 adjacent positions
                    int oy = p0 >> 3, ox0 = p0 & 7;     // ox0 in {0,4}
                    int wbase = wv * A1_S + col * A1_CH + (2 + oy) * A1_ROW + (2 + ox0);
                    unsigned* d32 = (unsigned*)&a1[wbase];   // wbase even
                    float t0 = fast_tanh(acc[0] + bf2f(b1s[col * 64 + p0 + 0]));
                    float t1 = fast_tanh(acc[1] + bf2f(b1s[col * 64 + p0 + 1]));
                    float t2 = fast_tanh(acc[2] + bf2f(b1s[col * 64 + p0 + 2]));
                    float t3 = fast_tanh(acc[3] + bf2f(b1s[col * 64 + p0 + 3]));
                    d32[0] = pack2bf(t0, t1);
                    d32[1] = pack2bf(t2, t3);
                }
            }
        }

        // ---- H2: A=patch, B=weights; two independent 6-MFMA chains ----
        {
            int sbase = wv * A1_S + q2;
            f32x4 acc0 = {0.f, 0.f, 0.f, 0.f};
            f32x4 acc1 = {0.f, 0.f, 0.f, 0.f};
            #pragma unroll
            for (int ic = 0; ic < 6; ++ic) {
                int b0 = (sbase + ic * A1_CH) >> 1;
                int b1i = (sbase + (ic + 6) * A1_CH) >> 1;
                short8 p0, p1;
                #pragma unroll
                for (int pp = 0; pp < 4; ++pp) {
                    unsigned r0 = a132[b0 + (po2[pp] >> 1)];
                    unsigned r1 = a132[b1i + (po2[pp] >> 1)];
                    p0[2 * pp]     = (short)(r0 & 0xffff);
                    p0[2 * pp + 1] = (short)(r0 >> 16);
                    p1[2 * pp]     = (short)(r1 & 0xffff);
                    p1[2 * pp + 1] = (short)(r1 >> 16);
                }
                acc0 = __builtin_amdgcn_mfma_f32_16x16x32_bf16(p0, aw2[ic], acc0, 0, 0, 0);
                acc1 = __builtin_amdgcn_mfma_f32_16x16x32_bf16(p1, aw2[ic + 6], acc1, 0, 0, 0);
            }
            int sg = (g & 3) * 4 + wv;   // r8 slot convention
            if (col < 12) {
                int p0 = 4 * hi;                        // 4 adjacent positions
                int ib = sg * A2_S + col * 16 + p0;     // even
                unsigned* d32 = (unsigned*)&a2[ib];
                float v0o = fast_tanh(acc0[0] + acc1[0] + b2s[col * 16 + p0 + 0]);
                float v1o = fast_tanh(acc0[1] + acc1[1] + b2s[col * 16 + p0 + 1]);
                float v2o = fast_tanh(acc0[2] + acc1[2] + b2s[col * 16 + p0 + 2]);
                float v3o = fast_tanh(acc0[3] + acc1[3] + b2s[col * 16 + p0 + 3]);
                d32[0] = pack2bf(v0o, v1o);
                d32[1] = pack2bf(v2o, v3o);
            }
        }

        // ---- every 4 groups: H3 (waves 0,1; N=16 slots) + out (wave 0) ----
        if ((g & 3) == 3) {
            __syncthreads();   // a2 (16 slots) complete
            if (wv < 2) {
                int rt = wv;
                f32x4 acc = {0.f, 0.f, 0.f, 0.f};
                #pragma unroll
                for (int kt = 0; kt < 6; ++kt) {
                    short8 a = *((const short8*)wf3 + (rt * 6 + kt) * 64 + lane);
                    short8 b = *(const short8*)&a2[col * A2_S + kt * 32 + 8 * hi];
                    acc = __builtin_amdgcn_mfma_f32_16x16x32_bf16(a, b, acc, 0, 0, 0);
                }
                #pragma unroll
                for (int jj = 0; jj < 4; ++jj) {
                    int unit = rt * 16 + hi * 4 + jj;
                    if (unit < 30)
                        a3[col * A3_S + unit] = f2bf(fast_tanh(acc[jj] + b3s[unit]));
                }
            }
            __syncthreads();   // a3 cross-wave
            if (wv == 0) {
                short8 b = *(const short8*)&a3[col * A3_S + 8 * hi];
                f32x4 acc = __builtin_amdgcn_mfma_f32_16x16x32_bf16(
                    awo, b, (f32x4){0.f, 0.f, 0.f, 0.f}, 0, 0, 0);
                size_t sw = (size_t)blockIdx.x * (NG * SPB) + (g >> 2) * 16 + col;
                #pragma unroll
                for (int jj = 0; jj < 4; ++jj) {
                    int row = hi * 4 + jj;
                    if (row < 10)
                        out[sw * 10 + row] = fast_tanh(acc[jj] + obs[row]);
                }
            }
            __syncthreads();   // a2/a3 free for next window
        }
    }
}

extern "C" void kernel_launch(void* const* d_in, const int* in_sizes, int n_in,
                              void* d_out, int out_size, void* d_ws, size_t ws_size,
                              hipStream_t stream) {
    const float* x  = (const float*)d_in[0];
    const float* w1 = (const float*)d_in[1];
    const float* b1 = (const float*)d_in[2];
    const float* w2 = (const float*)d_in[3];
    const float* b2 = (const float*)d_in[4];
    const float* w3 = (const float*)d_in[5];
    const float* b3 = (const float*)d_in[6];
    const float* ow = (const float*)d_in[7];
    const float* ob = (const float*)d_in[8];
    float* out = (float*)d_out;

    const int B = in_sizes[0] / 256;   // 65536 samples
    lenet_mfma<<<dim3(B / (SPB * NG)), dim3(256), 0, stream>>>(
        x, w1, b1, w2, b2, w3, b3, ow, ob, out);
}